// Round 6
// baseline (411.984 us; speedup 1.0000x reference)
//
#include <hip/hip_runtime.h>
#include <hip/hip_bf16.h>
#include <cstddef>
#include <cstdint>

#define Bn 4
#define Tn 2048
#define Cn 1024
#define Hn 16
#define Rn 256
static constexpr float SCALE = 0.125f; // 1/sqrt(64)

typedef __attribute__((ext_vector_type(8))) short bf16x8;  // 8 bf16 (4 VGPRs)
typedef __attribute__((ext_vector_type(4))) float f32x4;

__device__ inline short f2bf(float v) {
  return __builtin_bit_cast(short, __float2bfloat16(v));
}
__device__ inline float bf2f(short s) {
  return __builtin_bit_cast(float, (unsigned)(unsigned short)s << 16);
}

// async global->LDS, 16 B per lane; LDS dst = wave-uniform base + lane*16
__device__ inline void gld16(const short* g, short* l) {
  __builtin_amdgcn_global_load_lds(
      (const __attribute__((address_space(1))) unsigned*)g,
      (__attribute__((address_space(3))) unsigned*)l, 16, 0, 0);
}

// ---------------------------------------------------------------------------
// Fused fp32->bf16 convert for x|basis|vproj|oproj (contiguous dst in ws)
// + uv pack: u,v [H,R,S] -> uvb [H,128,R] (transposed, q|k concat).
// ---------------------------------------------------------------------------
#define NCVT 1343488  // 8-elem units: x 1048576 | basis 32768 | vp 131072 | op 131072
__global__ __launch_bounds__(256) void cvtall(
    const float* __restrict__ x, const float* __restrict__ basis,
    const float* __restrict__ vproj, const float* __restrict__ oproj,
    const float* __restrict__ U, const float* __restrict__ V,
    short* __restrict__ dst, short* __restrict__ uvb) {
  int gid = blockIdx.x * 256 + threadIdx.x;
  if (gid < NCVT) {
    const float* src;
    int off;
    if (gid < 1048576) { src = x; off = gid; }
    else if (gid < 1081344) { src = basis; off = gid - 1048576; }
    else if (gid < 1212416) { src = vproj; off = gid - 1081344; }
    else { src = oproj; off = gid - 1212416; }
    const float4* p = (const float4*)src + (size_t)off * 2;
    float4 a = p[0], b = p[1];
    bf16x8 o;
    o[0] = f2bf(a.x); o[1] = f2bf(a.y); o[2] = f2bf(a.z); o[3] = f2bf(a.w);
    o[4] = f2bf(b.x); o[5] = f2bf(b.y); o[6] = f2bf(b.z); o[7] = f2bf(b.w);
    *((bf16x8*)dst + gid) = o;
  } else if (gid < NCVT + 65536) {
    int base = (gid - NCVT) * 8;
    int r0 = base & 255, j = (base >> 8) & 127, h = base >> 15;
    bf16x8 o;
#pragma unroll
    for (int i = 0; i < 8; ++i) {
      int r = r0 + i;
      float v = (j < 64) ? U[((size_t)h * 256 + r) * 64 + j]
                         : V[((size_t)h * 256 + r) * 64 + (j - 64)];
      o[i] = f2bf(v);
    }
    *(bf16x8*)(uvb + base) = o;
  }
}

// ---------------------------------------------------------------------------
// transpose vtmp [bh][t][d] -> VT [bh][d][t]  (bf16, 64x64 tiles)
// ---------------------------------------------------------------------------
__global__ __launch_bounds__(256) void vtrans_k(const short* __restrict__ in,
                                                short* __restrict__ out) {
  __shared__ short L[64 * 72];
  const int tid = threadIdx.x;
  const int t0 = blockIdx.x * 64, bh = blockIdx.y;
#pragma unroll
  for (int p = 0; p < 2; ++p) {
    int c = tid + p * 256;
    int t = c >> 3, dseg = c & 7;
    bf16x8 v = *(const bf16x8*)(in + ((size_t)bh * Tn + t0 + t) * 64 + dseg * 8);
#pragma unroll
    for (int i = 0; i < 8; ++i) L[(dseg * 8 + i) * 72 + t] = v[i];
  }
  __syncthreads();
#pragma unroll
  for (int p = 0; p < 2; ++p) {
    int c = tid + p * 256;
    int d = c >> 3, tseg = c & 7;
    bf16x8 v = *(const bf16x8*)&L[d * 72 + tseg * 8];
    *(bf16x8*)(out + ((size_t)bh * 64 + d) * Tn + t0 + tseg * 8) = v;
  }
}

// ---------------------------------------------------------------------------
// bf16 MFMA GEMM (m97 recipe): 128x128 tile, BK=32, 4 waves (2x2 of 64x64).
// SMODE 0: bf16 C0[m*N+n]
// SMODE 1: per-head q|k split (blockIdx.z=h, N=128)
// SMODE 2: bf16 [B,H,T,D]
// SMODE 3: fp32 C0[m*N+n]
// ---------------------------------------------------------------------------
template <int SMODE, int BIAS>
__global__ __launch_bounds__(256) void gemm_mfma(
    const short* __restrict__ A, const short* __restrict__ Bm,
    const float* __restrict__ bias, void* __restrict__ C0,
    void* __restrict__ C1, int M, int N, int K, int bstride) {
  __shared__ short As[128 * 32];
  __shared__ short Bs[128 * 32];
  const int tid = threadIdx.x;
  const int lane = tid & 63, l16 = lane & 15, quad = lane >> 4;
  const int wave = tid >> 6;
  const int wm = (wave >> 1) * 64, wn = (wave & 1) * 64;
  const int m0 = blockIdx.x * 128, n0 = blockIdx.y * 128;
  const short* Bp = Bm + (size_t)blockIdx.z * bstride;

  f32x4 acc[4][4];
#pragma unroll
  for (int i = 0; i < 4; ++i)
#pragma unroll
    for (int j = 0; j < 4; ++j) acc[i][j] = f32x4{0.f, 0.f, 0.f, 0.f};

  const int arow = tid >> 2, achk = (tid & 3) * 8;
  for (int k0 = 0; k0 < K; k0 += 32) {
#pragma unroll
    for (int p = 0; p < 2; ++p) {
      gld16(A + (size_t)(m0 + p * 64 + arow) * K + k0 + achk,
            As + p * 2048 + tid * 8);
      gld16(Bp + (size_t)(n0 + p * 64 + arow) * K + k0 + achk,
            Bs + p * 2048 + tid * 8);
    }
    __syncthreads();
    bf16x8 af[4], bf[4];
#pragma unroll
    for (int i = 0; i < 4; ++i)
      af[i] = *(const bf16x8*)&As[(wm + i * 16 + l16) * 32 + quad * 8];
#pragma unroll
    for (int j = 0; j < 4; ++j)
      bf[j] = *(const bf16x8*)&Bs[(wn + j * 16 + l16) * 32 + quad * 8];
#pragma unroll
    for (int i = 0; i < 4; ++i)
#pragma unroll
      for (int j = 0; j < 4; ++j)
        acc[i][j] =
            __builtin_amdgcn_mfma_f32_16x16x32_bf16(af[i], bf[j], acc[i][j], 0, 0, 0);
    __syncthreads();
  }

  float bj[4];
#pragma unroll
  for (int j = 0; j < 4; ++j)
    bj[j] = BIAS ? bias[n0 + wn + j * 16 + l16] : 0.f;

#pragma unroll
  for (int i = 0; i < 4; ++i) {
#pragma unroll
    for (int r = 0; r < 4; ++r) {
      int m = m0 + wm + i * 16 + quad * 4 + r;
      int b = m >> 11, t = m & 2047;
#pragma unroll
      for (int j = 0; j < 4; ++j) {
        int n = n0 + wn + j * 16 + l16;
        float val = acc[i][j][r] + bj[j];
        if (SMODE == 0) {
          ((short*)C0)[(size_t)m * N + n] = f2bf(val);
        } else if (SMODE == 1) {
          int bh = b * Hn + (int)blockIdx.z;
          short* dst = (short*)(n < 64 ? C0 : C1);
          dst[((size_t)bh * Tn + t) * 64 + (n & 63)] = f2bf(val);
        } else if (SMODE == 2) {
          int h = n >> 6, d = n & 63;
          ((short*)C0)[(((size_t)(b * Hn + h)) * Tn + t) * 64 + d] = f2bf(val);
        } else {
          ((float*)C0)[(size_t)m * N + n] = val;
        }
      }
    }
  }
}

// ---------------------------------------------------------------------------
// MFMA flash attention v6: 256 q-rows/block (8 waves), double-buffered K/V
// staging with ONE barrier per tile-iter (prefetch window = full iteration).
// Work items per bh (12 blocks, heavy-first via grid(bh-major)):
//   qt 0..3 : single block, full key range (4qt+4 tiles, <=16)
//   qt 4..7 : two blocks, half key range each (2qt+2 tiles, <=16)
// No-max softmax (scores |s|<~0.5) => O,l partials additive across halves.
// ---------------------------------------------------------------------------
__constant__ unsigned char ORD6[12] = {12, 30, 31, 26, 27, 8,
                                       22, 23, 18, 19, 4, 0};
#define PP 72
__global__ __launch_bounds__(512, 4) void atn6(
    const short* __restrict__ Qg, const short* __restrict__ Kg,
    const short* __restrict__ VTg, short* __restrict__ Yb,
    short* __restrict__ Opart, float* __restrict__ Lpart) {
  __shared__ short Ks[2][64 * 64];
  __shared__ short Vt[2][64 * 64];
  __shared__ short Ps[8 * 16 * PP];

  const int tid = threadIdx.x;
  const int wave = tid >> 6, lane = tid & 63;
  const int l16 = lane & 15, quad = lane >> 4;
  const unsigned v = ORD6[blockIdx.y];
  const int qt = v >> 2, split = (v >> 1) & 1, half = v & 1;
  const int bh = blockIdx.x;
  const int wtrow = qt * 256 + wave * 32;
  const size_t kb = (size_t)bh * Tn * 64;
  const size_t vb = (size_t)bh * 64 * Tn;
  const int j0 = split ? half * (2 * qt + 2) : 0;
  const int jn = split ? (2 * qt + 2) : (4 * qt + 4);

  // Q fragments: 2 row-groups x 2 k-steps
  bf16x8 qf[2][2];
#pragma unroll
  for (int rg = 0; rg < 2; ++rg)
#pragma unroll
    for (int s = 0; s < 2; ++s)
      qf[rg][s] = *(const bf16x8*)(Qg + kb +
          (size_t)(wtrow + rg * 16 + l16) * 64 + s * 32 + quad * 8);

  f32x4 o[2][4];
#pragma unroll
  for (int rg = 0; rg < 2; ++rg)
#pragma unroll
    for (int dt = 0; dt < 4; ++dt) o[rg][dt] = f32x4{0.f, 0.f, 0.f, 0.f};
  float lp[2][4] = {{0.f, 0.f, 0.f, 0.f}, {0.f, 0.f, 0.f, 0.f}};

  // staging: 512 threads x 16B = one 64x64 bf16 tile per buffer per issue
  const int srow = tid >> 3;                  // 0..63
  const int sseg = (tid & 7) ^ (srow & 7);    // XOR chunk swizzle
#define STAGE6(buf, j)                                                        \
  {                                                                           \
    gld16(Kg + kb + (size_t)((j) * 64 + srow) * 64 + sseg * 8,                \
          &Ks[buf][tid * 8]);                                                 \
    gld16(VTg + vb + (size_t)srow * Tn + (j) * 64 + sseg * 8,                 \
          &Vt[buf][tid * 8]);                                                 \
  }

  STAGE6(0, j0);
  short* pw = &Ps[wave * 16 * PP];
  const int xs = l16 & 7;

  for (int jj = 0; jj < jn; ++jj) {
    const int j = j0 + jj;
    const int cb = jj & 1;
    __syncthreads();  // buf[cb] staged; all waves done reading buf[cb^1]
    if (jj + 1 < jn) STAGE6(cb ^ 1, j + 1);  // full-iteration prefetch window

    const bool act1 = (j * 64 <= wtrow + 31);
    const bool act0 = (j * 64 <= wtrow + 15);
    if (!act1) continue;  // wave still hits next barrier

    bf16x8 kf[4][2], vf[4][2];
#pragma unroll
    for (int ct = 0; ct < 4; ++ct)
#pragma unroll
      for (int s = 0; s < 2; ++s)
        kf[ct][s] = *(const bf16x8*)&Ks[cb][(ct * 16 + l16) * 64 +
                                           ((s * 4 + quad) ^ xs) * 8];
#pragma unroll
    for (int dt = 0; dt < 4; ++dt)
#pragma unroll
      for (int s = 0; s < 2; ++s)
        vf[dt][s] = *(const bf16x8*)&Vt[cb][(dt * 16 + l16) * 64 +
                                            ((s * 4 + quad) ^ xs) * 8];

#pragma unroll
    for (int rg = 0; rg < 2; ++rg) {
      if (rg == 0 && !act0) continue;
      f32x4 sa[4];
#pragma unroll
      for (int ct = 0; ct < 4; ++ct) {
        sa[ct] = f32x4{0.f, 0.f, 0.f, 0.f};
#pragma unroll
        for (int s = 0; s < 2; ++s)
          sa[ct] = __builtin_amdgcn_mfma_f32_16x16x32_bf16(
              qf[rg][s], kf[ct][s], sa[ct], 0, 0, 0);
      }
      const int rbase = wtrow + rg * 16;
      const bool full = (j * 64 + 63 <= rbase);
#pragma unroll
      for (int ct = 0; ct < 4; ++ct) {
        const int u = j * 64 + ct * 16 + l16;
#pragma unroll
        for (int r = 0; r < 4; ++r) {
          float e;
          if (full) {
            e = __expf(sa[ct][r] * SCALE);
          } else {
            const int t = rbase + quad * 4 + r;
            e = (u <= t) ? __expf(sa[ct][r] * SCALE) : 0.f;
          }
          lp[rg][r] += e;
          pw[(quad * 4 + r) * PP + ct * 16 + l16] = f2bf(e);
        }
      }
      bf16x8 pf[2];
#pragma unroll
      for (int s = 0; s < 2; ++s)
        pf[s] = *(const bf16x8*)&pw[l16 * PP + s * 32 + quad * 8];
#pragma unroll
      for (int dt = 0; dt < 4; ++dt)
#pragma unroll
        for (int s = 0; s < 2; ++s)
          o[rg][dt] = __builtin_amdgcn_mfma_f32_16x16x32_bf16(
              pf[s], vf[dt][s], o[rg][dt], 0, 0, 0);
    }
  }

  const int row = lane >> 2, cseg = lane & 3;
  if (!split) {
    const int b = bh >> 4, h = bh & 15;
#pragma unroll
    for (int rg = 0; rg < 2; ++rg) {
      float inv[4];
#pragma unroll
      for (int r = 0; r < 4; ++r) {
        float l = lp[rg][r];
        l += __shfl_xor(l, 1);
        l += __shfl_xor(l, 2);
        l += __shfl_xor(l, 4);
        l += __shfl_xor(l, 8);
        inv[r] = 1.f / l;
      }
#pragma unroll
      for (int dt = 0; dt < 4; ++dt)
#pragma unroll
        for (int r = 0; r < 4; ++r)
          pw[(quad * 4 + r) * PP + dt * 16 + l16] = f2bf(o[rg][dt][r] * inv[r]);
      bf16x8 y0 = *(const bf16x8*)&pw[row * PP + cseg * 16];
      bf16x8 y1 = *(const bf16x8*)&pw[row * PP + cseg * 16 + 8];
      short* dst = Yb + ((size_t)(b * Tn + wtrow + rg * 16 + row)) * Cn +
                   h * 64 + cseg * 16;
      *(bf16x8*)dst = y0;
      *(bf16x8*)(dst + 8) = y1;
    }
  } else {
    // unnormalized additive partials
    const int slot = (bh * 4 + (qt - 4)) * 2 + half;
#pragma unroll
    for (int rg = 0; rg < 2; ++rg) {
      float lred[4];
#pragma unroll
      for (int r = 0; r < 4; ++r) {
        float l = lp[rg][r];
        l += __shfl_xor(l, 1);
        l += __shfl_xor(l, 2);
        l += __shfl_xor(l, 4);
        l += __shfl_xor(l, 8);
        lred[r] = l;
      }
#pragma unroll
      for (int dt = 0; dt < 4; ++dt)
#pragma unroll
        for (int r = 0; r < 4; ++r)
          pw[(quad * 4 + r) * PP + dt * 16 + l16] = f2bf(o[rg][dt][r]);
      bf16x8 y0 = *(const bf16x8*)&pw[row * PP + cseg * 16];
      bf16x8 y1 = *(const bf16x8*)&pw[row * PP + cseg * 16 + 8];
      const int rrow = wave * 32 + rg * 16 + row;
      short* dst = Opart + ((size_t)slot * 256 + rrow) * 64 + cseg * 16;
      *(bf16x8*)dst = y0;
      *(bf16x8*)(dst + 8) = y1;
      if (l16 == 0) {
#pragma unroll
        for (int r = 0; r < 4; ++r)
          Lpart[slot * 256 + wave * 32 + rg * 16 + quad * 4 + r] = lred[r];
      }
    }
  }
}

// ---------------------------------------------------------------------------
// combine: for qt 4..7 (rows 1024..2047), y = (Oa + Ob) / (la + lb) -> yb
// ---------------------------------------------------------------------------
__global__ __launch_bounds__(256) void combine_k(
    const short* __restrict__ Opart, const float* __restrict__ Lpart,
    short* __restrict__ Yb) {
  int gid = blockIdx.x * 256 + threadIdx.x;  // 524288
  int seg = gid & 7, row = (gid >> 3) & 255, qtr = (gid >> 11) & 3,
      bh = gid >> 13;
  int slotA = (bh * 4 + qtr) * 2, slotB = slotA + 1;
  float la = Lpart[slotA * 256 + row], lb = Lpart[slotB * 256 + row];
  float inv = 1.f / (la + lb);
  bf16x8 a = *(const bf16x8*)(Opart + ((size_t)slotA * 256 + row) * 64 + seg * 8);
  bf16x8 b = *(const bf16x8*)(Opart + ((size_t)slotB * 256 + row) * 64 + seg * 8);
  bf16x8 y;
#pragma unroll
  for (int i = 0; i < 8; ++i) y[i] = f2bf((bf2f(a[i]) + bf2f(b[i])) * inv);
  int t = (qtr + 4) * 256 + row, bb = bh >> 4, h = bh & 15;
  *(bf16x8*)(Yb + ((size_t)(bb * Tn + t)) * Cn + h * 64 + seg * 8) = y;
}

// ---------------------------------------------------------------------------
extern "C" void kernel_launch(void* const* d_in, const int* in_sizes, int n_in,
                              void* d_out, int out_size, void* d_ws,
                              size_t ws_size, hipStream_t stream) {
  const float* x        = (const float*)d_in[0];
  const float* basis_w  = (const float*)d_in[1];
  const float* u_factor = (const float*)d_in[2];
  const float* v_factor = (const float*)d_in[3];
  const float* v_proj_w = (const float*)d_in[4];
  const float* v_proj_b = (const float*)d_in[5];
  const float* o_proj_w = (const float*)d_in[6];
  const float* o_proj_b = (const float*)d_in[7];
  float* out = (float*)d_out;

  char* ws = (char*)d_ws;
  const size_t NX = (size_t)Bn * Tn * Cn;          // 8,388,608
  short* xb      = (short*)ws; ws += NX * 2;       // contig with next 3 (cvtall)
  short* bwb     = (short*)ws; ws += (size_t)Rn * Cn * 2;
  short* vpb     = (short*)ws; ws += (size_t)Cn * Cn * 2;
  short* opb     = (short*)ws; ws += (size_t)Cn * Cn * 2;
  short* uvb     = (short*)ws; ws += (size_t)Hn * 128 * Rn * 2;
  short* latentb = (short*)ws; ws += (size_t)Bn * Tn * Rn * 2;
  short* Qb      = (short*)ws; ws += NX * 2;       // [bh,T,64]
  short* Kb      = (short*)ws; ws += NX * 2;
  short* vtmp    = (short*)ws; ws += NX * 2;       // [bh,T,64]
  short* VTb     = (short*)ws; ws += NX * 2;       // [bh,64,T]
  short* yb      = (short*)ws; ws += NX * 2;       // [8192,1024]
  short* Opart   = (short*)ws; ws += (size_t)512 * 256 * 64 * 2;  // 16.8 MB
  float* Lpart   = (float*)ws;                     // 512*256 f32

  dim3 blk(256);
  cvtall<<<dim3(5504), blk, 0, stream>>>(x, basis_w, v_proj_w, o_proj_w,
                                         u_factor, v_factor, xb, uvb);

  // latent = x @ basis^T : bf16 [8192,256]
  gemm_mfma<0, 0><<<dim3(64, 2, 1), blk, 0, stream>>>(
      xb, bwb, nullptr, latentb, nullptr, 8192, 256, 1024, 0);
  // q|k = latent @ uv[h]^T : per-head split into Qb, Kb
  gemm_mfma<1, 0><<<dim3(64, 1, 16), blk, 0, stream>>>(
      latentb, uvb, nullptr, Qb, Kb, 8192, 128, 256, 128 * 256);
  // v = x @ v_proj^T + b -> [bh,T,64]
  gemm_mfma<2, 1><<<dim3(64, 8, 1), blk, 0, stream>>>(
      xb, vpb, v_proj_b, vtmp, nullptr, 8192, 1024, 1024, 0);
  // V^T [bh,64,T]
  vtrans_k<<<dim3(32, 64), blk, 0, stream>>>(vtmp, VTb);
  // attention (256-row blocks, split-key) -> yb + partials
  atn6<<<dim3(64, 12), dim3(512), 0, stream>>>(Qb, Kb, VTb, yb, Opart, Lpart);
  combine_k<<<dim3(2048), blk, 0, stream>>>(Opart, Lpart, yb);
  // out = yb @ o_proj^T + b : fp32
  gemm_mfma<3, 1><<<dim3(64, 8, 1), blk, 0, stream>>>(
      yb, opb, o_proj_b, out, nullptr, 8192, 1024, 1024, 0);
}

// Round 7
// 312.360 us; speedup vs baseline: 1.3189x; 1.3189x over previous
//
#include <hip/hip_runtime.h>
#include <hip/hip_bf16.h>
#include <cstddef>
#include <cstdint>

#define Bn 4
#define Tn 2048
#define Cn 1024
#define Hn 16
#define Rn 256
static constexpr float SCALE = 0.125f; // 1/sqrt(64)

typedef __attribute__((ext_vector_type(8))) short bf16x8;  // 8 bf16 (4 VGPRs)
typedef __attribute__((ext_vector_type(4))) float f32x4;

__device__ inline short f2bf(float v) {
  return __builtin_bit_cast(short, __float2bfloat16(v));
}
__device__ inline float bf2f(short s) {
  return __builtin_bit_cast(float, (unsigned)(unsigned short)s << 16);
}

// async global->LDS, 16 B per lane; LDS dst = wave-uniform base + lane*16
__device__ inline void gld16(const short* g, short* l) {
  __builtin_amdgcn_global_load_lds(
      (const __attribute__((address_space(1))) unsigned*)g,
      (__attribute__((address_space(3))) unsigned*)l, 16, 0, 0);
}

// ---------------------------------------------------------------------------
// Fused fp32->bf16 convert for x|basis|vproj|oproj (contiguous dst in ws)
// + uv pack: u,v [H,R,S] -> uvb [H,128,R] (transposed, q|k concat).
// ---------------------------------------------------------------------------
#define NCVT 1343488  // 8-elem units: x 1048576 | basis 32768 | vp 131072 | op 131072
__global__ __launch_bounds__(256) void cvtall(
    const float* __restrict__ x, const float* __restrict__ basis,
    const float* __restrict__ vproj, const float* __restrict__ oproj,
    const float* __restrict__ U, const float* __restrict__ V,
    short* __restrict__ dst, short* __restrict__ uvb) {
  int gid = blockIdx.x * 256 + threadIdx.x;
  if (gid < NCVT) {
    const float* src;
    int off;
    if (gid < 1048576) { src = x; off = gid; }
    else if (gid < 1081344) { src = basis; off = gid - 1048576; }
    else if (gid < 1212416) { src = vproj; off = gid - 1081344; }
    else { src = oproj; off = gid - 1212416; }
    const float4* p = (const float4*)src + (size_t)off * 2;
    float4 a = p[0], b = p[1];
    bf16x8 o;
    o[0] = f2bf(a.x); o[1] = f2bf(a.y); o[2] = f2bf(a.z); o[3] = f2bf(a.w);
    o[4] = f2bf(b.x); o[5] = f2bf(b.y); o[6] = f2bf(b.z); o[7] = f2bf(b.w);
    *((bf16x8*)dst + gid) = o;
  } else if (gid < NCVT + 65536) {
    int base = (gid - NCVT) * 8;
    int r0 = base & 255, j = (base >> 8) & 127, h = base >> 15;
    bf16x8 o;
#pragma unroll
    for (int i = 0; i < 8; ++i) {
      int r = r0 + i;
      float v = (j < 64) ? U[((size_t)h * 256 + r) * 64 + j]
                         : V[((size_t)h * 256 + r) * 64 + (j - 64)];
      o[i] = f2bf(v);
    }
    *(bf16x8*)(uvb + base) = o;
  }
}

// ---------------------------------------------------------------------------
// transpose vtmp [bh][t][d] -> VT [bh][d][t]  (bf16, 64x64 tiles)
// ---------------------------------------------------------------------------
__global__ __launch_bounds__(256) void vtrans_k(const short* __restrict__ in,
                                                short* __restrict__ out) {
  __shared__ short L[64 * 72];
  const int tid = threadIdx.x;
  const int t0 = blockIdx.x * 64, bh = blockIdx.y;
#pragma unroll
  for (int p = 0; p < 2; ++p) {
    int c = tid + p * 256;
    int t = c >> 3, dseg = c & 7;
    bf16x8 v = *(const bf16x8*)(in + ((size_t)bh * Tn + t0 + t) * 64 + dseg * 8);
#pragma unroll
    for (int i = 0; i < 8; ++i) L[(dseg * 8 + i) * 72 + t] = v[i];
  }
  __syncthreads();
#pragma unroll
  for (int p = 0; p < 2; ++p) {
    int c = tid + p * 256;
    int d = c >> 3, tseg = c & 7;
    bf16x8 v = *(const bf16x8*)&L[d * 72 + tseg * 8];
    *(bf16x8*)(out + ((size_t)bh * 64 + d) * Tn + t0 + tseg * 8) = v;
  }
}

// ---------------------------------------------------------------------------
// bf16 MFMA GEMM (m97 recipe): 128x128 tile, BK=32, 4 waves (2x2 of 64x64).
// SMODE 0: bf16 C0[m*N+n]
// SMODE 1: per-head q|k split (blockIdx.z=h, N=128)
// SMODE 2: bf16 [B,H,T,D]
// SMODE 3: fp32 C0[m*N+n]
// ---------------------------------------------------------------------------
template <int SMODE, int BIAS>
__global__ __launch_bounds__(256) void gemm_mfma(
    const short* __restrict__ A, const short* __restrict__ Bm,
    const float* __restrict__ bias, void* __restrict__ C0,
    void* __restrict__ C1, int M, int N, int K, int bstride) {
  __shared__ short As[128 * 32];
  __shared__ short Bs[128 * 32];
  const int tid = threadIdx.x;
  const int lane = tid & 63, l16 = lane & 15, quad = lane >> 4;
  const int wave = tid >> 6;
  const int wm = (wave >> 1) * 64, wn = (wave & 1) * 64;
  const int m0 = blockIdx.x * 128, n0 = blockIdx.y * 128;
  const short* Bp = Bm + (size_t)blockIdx.z * bstride;

  f32x4 acc[4][4];
#pragma unroll
  for (int i = 0; i < 4; ++i)
#pragma unroll
    for (int j = 0; j < 4; ++j) acc[i][j] = f32x4{0.f, 0.f, 0.f, 0.f};

  const int arow = tid >> 2, achk = (tid & 3) * 8;
  for (int k0 = 0; k0 < K; k0 += 32) {
#pragma unroll
    for (int p = 0; p < 2; ++p) {
      gld16(A + (size_t)(m0 + p * 64 + arow) * K + k0 + achk,
            As + p * 2048 + tid * 8);
      gld16(Bp + (size_t)(n0 + p * 64 + arow) * K + k0 + achk,
            Bs + p * 2048 + tid * 8);
    }
    __syncthreads();
    bf16x8 af[4], bf[4];
#pragma unroll
    for (int i = 0; i < 4; ++i)
      af[i] = *(const bf16x8*)&As[(wm + i * 16 + l16) * 32 + quad * 8];
#pragma unroll
    for (int j = 0; j < 4; ++j)
      bf[j] = *(const bf16x8*)&Bs[(wn + j * 16 + l16) * 32 + quad * 8];
#pragma unroll
    for (int i = 0; i < 4; ++i)
#pragma unroll
      for (int j = 0; j < 4; ++j)
        acc[i][j] =
            __builtin_amdgcn_mfma_f32_16x16x32_bf16(af[i], bf[j], acc[i][j], 0, 0, 0);
    __syncthreads();
  }

  float bj[4];
#pragma unroll
  for (int j = 0; j < 4; ++j)
    bj[j] = BIAS ? bias[n0 + wn + j * 16 + l16] : 0.f;

#pragma unroll
  for (int i = 0; i < 4; ++i) {
#pragma unroll
    for (int r = 0; r < 4; ++r) {
      int m = m0 + wm + i * 16 + quad * 4 + r;
      int b = m >> 11, t = m & 2047;
#pragma unroll
      for (int j = 0; j < 4; ++j) {
        int n = n0 + wn + j * 16 + l16;
        float val = acc[i][j][r] + bj[j];
        if (SMODE == 0) {
          ((short*)C0)[(size_t)m * N + n] = f2bf(val);
        } else if (SMODE == 1) {
          int bh = b * Hn + (int)blockIdx.z;
          short* dst = (short*)(n < 64 ? C0 : C1);
          dst[((size_t)bh * Tn + t) * 64 + (n & 63)] = f2bf(val);
        } else if (SMODE == 2) {
          int h = n >> 6, d = n & 63;
          ((short*)C0)[(((size_t)(b * Hn + h)) * Tn + t) * 64 + d] = f2bf(val);
        } else {
          ((float*)C0)[(size_t)m * N + n] = val;
        }
      }
    }
  }
}

// ---------------------------------------------------------------------------
// MFMA flash attention v7 = v6 structure with the spill fixed:
// __launch_bounds__(512) only (no min-waves clause -> no VGPR squeeze), and
// short fragment live-ranges (kf consumed per-ct, vf loaded per-dt in PV).
// 256 q-rows/block (8 waves), double-buffered K/V staging, ONE barrier/iter.
// Work per bh (12 blocks, heavy-first): qt 0..3 full range; qt 4..7 2-way
// key-split (additive no-max-softmax partials, combined by combine_k).
// ---------------------------------------------------------------------------
__constant__ unsigned char ORD6[12] = {12, 30, 31, 26, 27, 8,
                                       22, 23, 18, 19, 4, 0};
#define PP 72
__global__ __launch_bounds__(512) void atn7(
    const short* __restrict__ Qg, const short* __restrict__ Kg,
    const short* __restrict__ VTg, short* __restrict__ Yb,
    short* __restrict__ Opart, float* __restrict__ Lpart) {
  __shared__ short Ks[2][64 * 64];
  __shared__ short Vt[2][64 * 64];
  __shared__ short Ps[8 * 16 * PP];

  const int tid = threadIdx.x;
  const int wave = tid >> 6, lane = tid & 63;
  const int l16 = lane & 15, quad = lane >> 4;
  const unsigned v = ORD6[blockIdx.y];
  const int qt = v >> 2, split = (v >> 1) & 1, half = v & 1;
  const int bh = blockIdx.x;
  const int wtrow = qt * 256 + wave * 32;
  const size_t kb = (size_t)bh * Tn * 64;
  const size_t vb = (size_t)bh * 64 * Tn;
  const int j0 = split ? half * (2 * qt + 2) : 0;
  const int jn = split ? (2 * qt + 2) : (4 * qt + 4);

  // Q fragments: 2 row-groups x 2 k-steps
  bf16x8 qf[2][2];
#pragma unroll
  for (int rg = 0; rg < 2; ++rg)
#pragma unroll
    for (int s = 0; s < 2; ++s)
      qf[rg][s] = *(const bf16x8*)(Qg + kb +
          (size_t)(wtrow + rg * 16 + l16) * 64 + s * 32 + quad * 8);

  f32x4 o[2][4];
#pragma unroll
  for (int rg = 0; rg < 2; ++rg)
#pragma unroll
    for (int dt = 0; dt < 4; ++dt) o[rg][dt] = f32x4{0.f, 0.f, 0.f, 0.f};
  float lp[2][4] = {{0.f, 0.f, 0.f, 0.f}, {0.f, 0.f, 0.f, 0.f}};

  // staging: 512 threads x 16B = one 64x64 bf16 tile per buffer per issue
  const int srow = tid >> 3;                  // 0..63
  const int sseg = (tid & 7) ^ (srow & 7);    // XOR chunk swizzle
#define STAGE7(buf, j)                                                        \
  {                                                                           \
    gld16(Kg + kb + (size_t)((j) * 64 + srow) * 64 + sseg * 8,                \
          &Ks[buf][tid * 8]);                                                 \
    gld16(VTg + vb + (size_t)srow * Tn + (j) * 64 + sseg * 8,                 \
          &Vt[buf][tid * 8]);                                                 \
  }

  STAGE7(0, j0);
  short* pw = &Ps[wave * 16 * PP];
  const int xs = l16 & 7;

  for (int jj = 0; jj < jn; ++jj) {
    const int j = j0 + jj;
    const int cb = jj & 1;
    __syncthreads();  // buf[cb] staged; all waves done reading buf[cb^1]
    if (jj + 1 < jn) STAGE7(cb ^ 1, j + 1);  // full-iteration prefetch window

    const bool act1 = (j * 64 <= wtrow + 31);
    const bool act0 = (j * 64 <= wtrow + 15);
    if (!act1) continue;  // wave still hits next barrier

    // QK^T: consume K frags per-ct (short live range)
    f32x4 sa[2][4];
#pragma unroll
    for (int ct = 0; ct < 4; ++ct) {
      bf16x8 k0 = *(const bf16x8*)&Ks[cb][(ct * 16 + l16) * 64 + ((0 + quad) ^ xs) * 8];
      bf16x8 k1 = *(const bf16x8*)&Ks[cb][(ct * 16 + l16) * 64 + ((4 + quad) ^ xs) * 8];
#pragma unroll
      for (int rg = 0; rg < 2; ++rg) {
        if (rg == 0 && !act0) continue;
        f32x4 t = f32x4{0.f, 0.f, 0.f, 0.f};
        t = __builtin_amdgcn_mfma_f32_16x16x32_bf16(qf[rg][0], k0, t, 0, 0, 0);
        t = __builtin_amdgcn_mfma_f32_16x16x32_bf16(qf[rg][1], k1, t, 0, 0, 0);
        sa[rg][ct] = t;
      }
    }

#pragma unroll
    for (int rg = 0; rg < 2; ++rg) {
      if (rg == 0 && !act0) continue;
      const int rbase = wtrow + rg * 16;
      const bool full = (j * 64 + 63 <= rbase);
#pragma unroll
      for (int ct = 0; ct < 4; ++ct) {
        const int u = j * 64 + ct * 16 + l16;
#pragma unroll
        for (int r = 0; r < 4; ++r) {
          float e;
          if (full) {
            e = __expf(sa[rg][ct][r] * SCALE);
          } else {
            const int t = rbase + quad * 4 + r;
            e = (u <= t) ? __expf(sa[rg][ct][r] * SCALE) : 0.f;
          }
          lp[rg][r] += e;
          pw[(quad * 4 + r) * PP + ct * 16 + l16] = f2bf(e);
        }
      }
      bf16x8 pf0 = *(const bf16x8*)&pw[l16 * PP + quad * 8];
      bf16x8 pf1 = *(const bf16x8*)&pw[l16 * PP + 32 + quad * 8];
      // PV: load V^T frags per-dt (short live range)
#pragma unroll
      for (int dt = 0; dt < 4; ++dt) {
        bf16x8 v0 = *(const bf16x8*)&Vt[cb][(dt * 16 + l16) * 64 + ((0 + quad) ^ xs) * 8];
        bf16x8 v1 = *(const bf16x8*)&Vt[cb][(dt * 16 + l16) * 64 + ((4 + quad) ^ xs) * 8];
        o[rg][dt] = __builtin_amdgcn_mfma_f32_16x16x32_bf16(pf0, v0, o[rg][dt], 0, 0, 0);
        o[rg][dt] = __builtin_amdgcn_mfma_f32_16x16x32_bf16(pf1, v1, o[rg][dt], 0, 0, 0);
      }
    }
  }

  const int row = lane >> 2, cseg = lane & 3;
  if (!split) {
    const int b = bh >> 4, h = bh & 15;
#pragma unroll
    for (int rg = 0; rg < 2; ++rg) {
      float inv[4];
#pragma unroll
      for (int r = 0; r < 4; ++r) {
        float l = lp[rg][r];
        l += __shfl_xor(l, 1);
        l += __shfl_xor(l, 2);
        l += __shfl_xor(l, 4);
        l += __shfl_xor(l, 8);
        inv[r] = 1.f / l;
      }
#pragma unroll
      for (int dt = 0; dt < 4; ++dt)
#pragma unroll
        for (int r = 0; r < 4; ++r)
          pw[(quad * 4 + r) * PP + dt * 16 + l16] = f2bf(o[rg][dt][r] * inv[r]);
      bf16x8 y0 = *(const bf16x8*)&pw[row * PP + cseg * 16];
      bf16x8 y1 = *(const bf16x8*)&pw[row * PP + cseg * 16 + 8];
      short* dst = Yb + ((size_t)(b * Tn + wtrow + rg * 16 + row)) * Cn +
                   h * 64 + cseg * 16;
      *(bf16x8*)dst = y0;
      *(bf16x8*)(dst + 8) = y1;
    }
  } else {
    // unnormalized additive partials
    const int slot = (bh * 4 + (qt - 4)) * 2 + half;
#pragma unroll
    for (int rg = 0; rg < 2; ++rg) {
      float lred[4];
#pragma unroll
      for (int r = 0; r < 4; ++r) {
        float l = lp[rg][r];
        l += __shfl_xor(l, 1);
        l += __shfl_xor(l, 2);
        l += __shfl_xor(l, 4);
        l += __shfl_xor(l, 8);
        lred[r] = l;
      }
#pragma unroll
      for (int dt = 0; dt < 4; ++dt)
#pragma unroll
        for (int r = 0; r < 4; ++r)
          pw[(quad * 4 + r) * PP + dt * 16 + l16] = f2bf(o[rg][dt][r]);
      bf16x8 y0 = *(const bf16x8*)&pw[row * PP + cseg * 16];
      bf16x8 y1 = *(const bf16x8*)&pw[row * PP + cseg * 16 + 8];
      const int rrow = wave * 32 + rg * 16 + row;
      short* dst = Opart + ((size_t)slot * 256 + rrow) * 64 + cseg * 16;
      *(bf16x8*)dst = y0;
      *(bf16x8*)(dst + 8) = y1;
      if (l16 == 0) {
#pragma unroll
        for (int r = 0; r < 4; ++r)
          Lpart[slot * 256 + wave * 32 + rg * 16 + quad * 4 + r] = lred[r];
      }
    }
  }
}

// ---------------------------------------------------------------------------
// combine: for qt 4..7 (rows 1024..2047), y = (Oa + Ob) / (la + lb) -> yb
// ---------------------------------------------------------------------------
__global__ __launch_bounds__(256) void combine_k(
    const short* __restrict__ Opart, const float* __restrict__ Lpart,
    short* __restrict__ Yb) {
  int gid = blockIdx.x * 256 + threadIdx.x;  // 524288
  int seg = gid & 7, row = (gid >> 3) & 255, qtr = (gid >> 11) & 3,
      bh = gid >> 13;
  int slotA = (bh * 4 + qtr) * 2, slotB = slotA + 1;
  float la = Lpart[slotA * 256 + row], lb = Lpart[slotB * 256 + row];
  float inv = 1.f / (la + lb);
  bf16x8 a = *(const bf16x8*)(Opart + ((size_t)slotA * 256 + row) * 64 + seg * 8);
  bf16x8 b = *(const bf16x8*)(Opart + ((size_t)slotB * 256 + row) * 64 + seg * 8);
  bf16x8 y;
#pragma unroll
  for (int i = 0; i < 8; ++i) y[i] = f2bf((bf2f(a[i]) + bf2f(b[i])) * inv);
  int t = (qtr + 4) * 256 + row, bb = bh >> 4, h = bh & 15;
  *(bf16x8*)(Yb + ((size_t)(bb * Tn + t)) * Cn + h * 64 + seg * 8) = y;
}

// ---------------------------------------------------------------------------
extern "C" void kernel_launch(void* const* d_in, const int* in_sizes, int n_in,
                              void* d_out, int out_size, void* d_ws,
                              size_t ws_size, hipStream_t stream) {
  const float* x        = (const float*)d_in[0];
  const float* basis_w  = (const float*)d_in[1];
  const float* u_factor = (const float*)d_in[2];
  const float* v_factor = (const float*)d_in[3];
  const float* v_proj_w = (const float*)d_in[4];
  const float* v_proj_b = (const float*)d_in[5];
  const float* o_proj_w = (const float*)d_in[6];
  const float* o_proj_b = (const float*)d_in[7];
  float* out = (float*)d_out;

  char* ws = (char*)d_ws;
  const size_t NX = (size_t)Bn * Tn * Cn;          // 8,388,608
  short* xb      = (short*)ws; ws += NX * 2;       // contig with next 3 (cvtall)
  short* bwb     = (short*)ws; ws += (size_t)Rn * Cn * 2;
  short* vpb     = (short*)ws; ws += (size_t)Cn * Cn * 2;
  short* opb     = (short*)ws; ws += (size_t)Cn * Cn * 2;
  short* uvb     = (short*)ws; ws += (size_t)Hn * 128 * Rn * 2;
  short* latentb = (short*)ws; ws += (size_t)Bn * Tn * Rn * 2;
  short* Qb      = (short*)ws; ws += NX * 2;       // [bh,T,64]
  short* Kb      = (short*)ws; ws += NX * 2;
  short* vtmp    = (short*)ws; ws += NX * 2;       // [bh,T,64]
  short* VTb     = (short*)ws; ws += NX * 2;       // [bh,64,T]
  short* yb      = (short*)ws; ws += NX * 2;       // [8192,1024]
  short* Opart   = (short*)ws; ws += (size_t)512 * 256 * 64 * 2;  // 16.8 MB
  float* Lpart   = (float*)ws;                     // 512*256 f32

  dim3 blk(256);
  cvtall<<<dim3(5504), blk, 0, stream>>>(x, basis_w, v_proj_w, o_proj_w,
                                         u_factor, v_factor, xb, uvb);

  // latent = x @ basis^T : bf16 [8192,256]
  gemm_mfma<0, 0><<<dim3(64, 2, 1), blk, 0, stream>>>(
      xb, bwb, nullptr, latentb, nullptr, 8192, 256, 1024, 0);
  // q|k = latent @ uv[h]^T : per-head split into Qb, Kb
  gemm_mfma<1, 0><<<dim3(64, 1, 16), blk, 0, stream>>>(
      latentb, uvb, nullptr, Qb, Kb, 8192, 128, 256, 128 * 256);
  // v = x @ v_proj^T + b -> [bh,T,64]
  gemm_mfma<2, 1><<<dim3(64, 8, 1), blk, 0, stream>>>(
      xb, vpb, v_proj_b, vtmp, nullptr, 8192, 1024, 1024, 0);
  // V^T [bh,64,T]
  vtrans_k<<<dim3(32, 64), blk, 0, stream>>>(vtmp, VTb);
  // attention (256-row blocks, dbuf staging, split-key) -> yb + partials
  atn7<<<dim3(64, 12), dim3(512), 0, stream>>>(Qb, Kb, VTb, yb, Opart, Lpart);
  combine_k<<<dim3(2048), blk, 0, stream>>>(Opart, Lpart, yb);
  // out = yb @ o_proj^T + b : fp32
  gemm_mfma<3, 1><<<dim3(64, 8, 1), blk, 0, stream>>>(
      yb, opb, o_proj_b, out, nullptr, 8192, 1024, 1024, 0);
}